// Round 11
// baseline (504.836 us; speedup 1.0000x reference)
//
#include <hip/hip_runtime.h>

// VGRUd v11 — 64-row blocks, 8 balanced dual-role waves, 4 waves/SIMD.
// 512 blocks x 512 thr; LDS 43008 B -> 2 blocks/CU = 16 waves/CU.
// Wave w: GATES: col-slice jt=w&3, row-half rh=w>>2 (mt rh*2, rh*2+1):
//   weights persistent in VGPR (64), 48 MFMA/step, exp2 epilogue.
// LOGITS: rows (w&3)*16, computed by BOTH waves of pair (w, w+4); stores split
//   (w<4: cols 0..47, w>=4: cols 48..77). 2-term emulation (wd-lo dropped).
// Pair (w, w+4) shares a SIMD with opposite phase order -> pipe diversity.
// h pre-split hi/lo bf16 planes in MFMA-frag layout, double-buffered.
// Light barrier (lgkmcnt only) once per step; exp2-prescaled weights.
// Step 1 (K=192) fused via 6 staged K=32 chunks aliasing wd+h arena.

typedef short bf16x8 __attribute__((ext_vector_type(8)));
typedef float f32x4 __attribute__((ext_vector_type(4)));

#define TPB 512
#define LOG2E 1.44269504088896f
#define S2E   2.88539008177793f

__device__ __forceinline__ unsigned pack_hi16(float a, float b) {
  return __builtin_amdgcn_perm(__float_as_uint(b), __float_as_uint(a), 0x07060302u);
}
__device__ __forceinline__ float truncbf(float a) {
  return __uint_as_float(__float_as_uint(a) & 0xffff0000u);
}
template <int CTRL>
__device__ __forceinline__ float dppror(float x) {
  return __int_as_float(
      __builtin_amdgcn_update_dpp(0, __float_as_int(x), CTRL, 0xf, 0xf, true));
}
__device__ __forceinline__ void split8(const float f[8], bf16x8& ah, bf16x8& al) {
  uint4 ph, pl;
  ph.x = pack_hi16(f[0], f[1]); ph.y = pack_hi16(f[2], f[3]);
  ph.z = pack_hi16(f[4], f[5]); ph.w = pack_hi16(f[6], f[7]);
  pl.x = pack_hi16(f[0] - truncbf(f[0]), f[1] - truncbf(f[1]));
  pl.y = pack_hi16(f[2] - truncbf(f[2]), f[3] - truncbf(f[3]));
  pl.z = pack_hi16(f[4] - truncbf(f[4]), f[5] - truncbf(f[5]));
  pl.w = pack_hi16(f[6] - truncbf(f[6]), f[7] - truncbf(f[7]));
  ah = __builtin_bit_cast(bf16x8, ph);
  al = __builtin_bit_cast(bf16x8, pl);
}
__device__ __forceinline__ void light_barrier() {
  __builtin_amdgcn_sched_barrier(0);
  asm volatile("s_waitcnt lgkmcnt(0)" ::: "memory");
  __builtin_amdgcn_s_barrier();
  __builtin_amdgcn_sched_barrier(0);
}

#define MFMA __builtin_amdgcn_mfma_f32_16x16x32_bf16
#define EXP2 __builtin_amdgcn_exp2f
#define RCP  __builtin_amdgcn_rcpf

__global__ __launch_bounds__(TPB, 4) void vgru_all(
    const float* __restrict__ x, const float* __restrict__ Hin,
    const float* __restrict__ Wk, const float* __restrict__ Uk,
    const float* __restrict__ bias, const float* __restrict__ Wd,
    const float* __restrict__ bd, float* __restrict__ out)
{
  extern __shared__ float smem[];
  // final: wdHi [0,2560) f; h arena [2560,10752) f = 16384 ush.
  //   h buf p: ush offset p*8192; hi [0,4096), lo [4096,8192).
  //   element (mt,ks,g,n,j): ((mt*2+ks)*4+g)*16+n)*8+j  (mt 0..3)
  // step-1 transient: chkHi [0,4096) f, chkLo [4096,8192) f.
  float* wdHi = smem;
  unsigned short* hbase = (unsigned short*)(smem + 2560);
  float* chkHi = smem;
  float* chkLo = smem + 4096;

  const int tid  = threadIdx.x;
  const int lane = tid & 63, w = tid >> 6;   // w in 0..7
  const int g = lane >> 4, n = lane & 15;
  const int jt = w & 3;                      // gate col-slice
  const int rh = w >> 2;                     // gate row-half (mt pair)
  const int lt = w & 3;                      // logits mt (rows lt*16..+16)
  const bool storeLow = (w < 4);
  const int blockbase = blockIdx.x * 64;
  const float* b0 = bias;
  const float* b1 = bias + 192;

  // per-lane gate biases (prescaled)
  const int cb = jt * 16 + n;
  const float bz  = (b0[cb] + b1[cb]) * LOG2E;
  const float brr = (b0[64 + cb] + b1[64 + cb]) * LOG2E;
  const float bxh = b0[128 + cb] * S2E;
  const float bhh = b1[128 + cb] * S2E;

  // ---- step 1: h1 = gru(x, H), K=192 in 6 chunks of K=32 ----
  f32x4 G0[2][4];  // [mtl][gate]
  #pragma unroll
  for (int mtl = 0; mtl < 2; ++mtl) {
    G0[mtl][0] = (f32x4){bz, bz, bz, bz};
    G0[mtl][1] = (f32x4){brr, brr, brr, brr};
    G0[mtl][2] = (f32x4){bxh, bxh, bxh, bxh};
    G0[mtl][3] = (f32x4){bhh, bhh, bhh, bhh};
  }

  for (int t = 0; t < 6; ++t) {
    for (int idx = tid; idx < 1024; idx += TPB) {
      int fr = idx >> 6, ln = idx & 63;      // fr = col-tile 0..15
      int lg = ln >> 4, lnn = ln & 15;
      int c = fr * 16 + lnn;
      float scale = (c < 128) ? LOG2E : S2E;
      float f[8];
      #pragma unroll
      for (int j = 0; j < 8; ++j) {
        int k = t * 32 + lg * 8 + j;
        float v;
        if (k < 128) v = (c < 192) ? Wk[k * 192 + c] : 0.0f;
        else {
          int ku = k - 128;
          v = (c < 128) ? Uk[ku * 192 + c]
                        : ((c < 192) ? 0.0f : Uk[ku * 192 + 128 + (c - 192)]);
        }
        f[j] = v * scale;
      }
      bf16x8 h8, l8; split8(f, h8, l8);
      ((bf16x8*)chkHi)[fr * 64 + ln] = h8;
      ((bf16x8*)chkLo)[fr * 64 + ln] = l8;
    }
    __syncthreads();
    {
      bf16x8 Ah[2], Al[2];
      #pragma unroll
      for (int mtl = 0; mtl < 2; ++mtl) {
        int row = blockbase + (rh * 2 + mtl) * 16 + n;
        const float* src = (t < 4)
            ? x + (size_t)row * 128 + t * 32 + g * 8
            : Hin + (size_t)row * 64 + (t - 4) * 32 + g * 8;
        float4 v0 = *(const float4*)src;
        float4 v1 = *(const float4*)(src + 4);
        float f[8] = {v0.x, v0.y, v0.z, v0.w, v1.x, v1.y, v1.z, v1.w};
        split8(f, Ah[mtl], Al[mtl]);
      }
      __builtin_amdgcn_s_setprio(1);
      #pragma unroll
      for (int gg = 0; gg < 4; ++gg) {
        int ntb = gg * 4 + jt;
        bf16x8 wh = ((const bf16x8*)chkHi)[ntb * 64 + lane];
        bf16x8 wl = ((const bf16x8*)chkLo)[ntb * 64 + lane];
        #pragma unroll
        for (int mtl = 0; mtl < 2; ++mtl) {
          G0[mtl][gg] = MFMA(Ah[mtl], wh, G0[mtl][gg], 0, 0, 0);
          G0[mtl][gg] = MFMA(Al[mtl], wh, G0[mtl][gg], 0, 0, 0);
          G0[mtl][gg] = MFMA(Ah[mtl], wl, G0[mtl][gg], 0, 0, 0);
        }
      }
      __builtin_amdgcn_s_setprio(0);
    }
    __syncthreads();
  }

  // step-1 epilogue -> hold regs + pre-split h1 into buf0 (chk dead now)
  float hold[8];
  const int ksw = jt >> 1;
  const int gw  = (jt * 2 + (n >> 3)) & 3;
  const int jw  = n & 7;
  {
    unsigned short* h0Hi = hbase;
    unsigned short* h0Lo = hbase + 4096;
    #pragma unroll
    for (int mtl = 0; mtl < 2; ++mtl) {
      int mtg = rh * 2 + mtl;
      #pragma unroll
      for (int rr = 0; rr < 4; ++rr) {
        int lrow = mtg * 16 + g * 4 + rr;
        float h0 = Hin[(size_t)(blockbase + lrow) * 64 + cb];
        float z  = RCP(1.0f + EXP2(-G0[mtl][0][rr]));
        float rg = RCP(1.0f + EXP2(-G0[mtl][1][rr]));
        float y  = G0[mtl][2][rr] + rg * G0[mtl][3][rr];
        float cand = 1.0f - 2.0f * RCP(EXP2(y) + 1.0f);
        float hv = cand + z * (h0 - cand);
        hold[mtl * 4 + rr] = hv;
        int off = (((mtg * 2 + ksw) * 4 + gw) * 16 + (g * 4 + rr)) * 8 + jw;
        unsigned u = __float_as_uint(hv);
        float lov = hv - truncbf(hv);
        h0Hi[off] = (unsigned short)(u >> 16);
        h0Lo[off] = (unsigned short)(__float_as_uint(lov) >> 16);
      }
    }
  }

  // ---- stage Wd hi frags (prescaled) into [0,2560) (chk dead) ----
  // NOTE: must come after step-1 epilogue writes? No overlap: wd [0,2560)f is
  // inside old chk region, h arena starts at 2560 -> disjoint. Need all chk
  // reads done: the t-loop's trailing __syncthreads covers it.
  for (int idx = tid; idx < 640; idx += TPB) {
    int fr = idx >> 6, ln = idx & 63;
    int nt = fr >> 1, ks = fr & 1;
    int lg = ln >> 4, lnn = ln & 15;
    int c = nt * 16 + lnn;
    float f[8];
    #pragma unroll
    for (int j = 0; j < 8; ++j) {
      int k = ks * 32 + lg * 8 + j;
      f[j] = (c < 78) ? Wd[k * 78 + c] * LOG2E : 0.0f;
    }
    bf16x8 h8, l8; split8(f, h8, l8);
    ((bf16x8*)wdHi)[fr * 64 + ln] = h8;
  }

  // ---- persistent gate weights (jt slice, prescaled) -> VGPR ----
  bf16x8 Wh[4][2], Wl[4][2];
  #pragma unroll
  for (int gg = 0; gg < 4; ++gg)
    #pragma unroll
    for (int ks = 0; ks < 2; ++ks) {
      int c = (gg * 4 + jt) * 16 + n;
      float scale = (c < 128) ? LOG2E : S2E;
      float f[8];
      #pragma unroll
      for (int j = 0; j < 8; ++j) {
        int k = ks * 32 + g * 8 + j;
        float v;
        if      (c < 128) v = Wk[k * 192 + c] + Uk[k * 192 + c];
        else if (c < 192) v = Wk[k * 192 + c];
        else              v = Uk[k * 192 + 128 + (c - 192)];
        f[j] = v * scale;
      }
      split8(f, Wh[gg][ks], Wl[gg][ks]);
    }
  float bdv[5];
  #pragma unroll
  for (int nt = 0; nt < 5; ++nt) {
    int c = nt * 16 + n;
    bdv[nt] = (c < 78) ? bd[c] * LOG2E : 0.0f;
  }
  __syncthreads();

  // ---- 25 iterations ----
  #pragma unroll 1
  for (int s = 0; s < 25; ++s) {
    const unsigned short* curHi = hbase + (s & 1) * 8192;
    const unsigned short* curLo = curHi + 4096;
    unsigned short* nxtHi = hbase + ((s + 1) & 1) * 8192;
    unsigned short* nxtLo = nxtHi + 4096;

    auto do_logits = [&]() {
      bf16x8 Ah[2], Al[2];
      #pragma unroll
      for (int ks = 0; ks < 2; ++ks) {
        int off = (((lt * 2 + ks) * 4 + g) * 16 + n) * 8;
        Ah[ks] = *(const bf16x8*)(curHi + off);
        Al[ks] = *(const bf16x8*)(curLo + off);
      }
      f32x4 L[5];
      #pragma unroll
      for (int nt = 0; nt < 5; ++nt)
        L[nt] = (f32x4){bdv[nt], bdv[nt], bdv[nt], bdv[nt]};
      __builtin_amdgcn_s_setprio(1);
      #pragma unroll
      for (int nt = 0; nt < 5; ++nt)
        #pragma unroll
        for (int ks = 0; ks < 2; ++ks) {
          bf16x8 wh = ((const bf16x8*)wdHi)[(nt * 2 + ks) * 64 + lane];
          L[nt] = MFMA(Ah[ks], wh, L[nt], 0, 0, 0);
          L[nt] = MFMA(Al[ks], wh, L[nt], 0, 0, 0);
        }
      __builtin_amdgcn_s_setprio(0);
      #pragma unroll
      for (int rr = 0; rr < 4; ++rr) {
        float e0 = EXP2(L[0][rr]);
        float e1 = EXP2(L[1][rr]);
        float e2 = EXP2(L[2][rr]);
        float e3 = EXP2(L[3][rr]);
        float e4 = (n < 14) ? EXP2(L[4][rr]) : 0.0f;
        float sm = e0 + e1 + e2 + e3 + e4;
        sm += dppror<0x128>(sm);
        sm += dppror<0x124>(sm);
        sm += dppror<0x122>(sm);
        sm += dppror<0x121>(sm);
        float inv = RCP(sm);
        size_t grow = (size_t)blockbase + lt * 16 + g * 4 + rr;
        float* orow = out + (grow * 25 + s) * 78;
        if (storeLow) {
          orow[n]      = e0 * inv;
          orow[16 + n] = e1 * inv;
          orow[32 + n] = e2 * inv;
        } else {
          orow[48 + n] = e3 * inv;
          if (n < 14) orow[64 + n] = e4 * inv;
        }
      }
    };

    auto do_gates = [&]() {
      #pragma unroll
      for (int mtl = 0; mtl < 2; ++mtl) {
        int mtg = rh * 2 + mtl;
        f32x4 C0 = {bz, bz, bz, bz};
        f32x4 C1 = {brr, brr, brr, brr};
        f32x4 C2 = {bxh, bxh, bxh, bxh};
        f32x4 C3 = {bhh, bhh, bhh, bhh};
        bf16x8 Ah0, Al0, Ah1, Al1;
        {
          int off0 = (((mtg * 2 + 0) * 4 + g) * 16 + n) * 8;
          int off1 = (((mtg * 2 + 1) * 4 + g) * 16 + n) * 8;
          Ah0 = *(const bf16x8*)(curHi + off0);
          Al0 = *(const bf16x8*)(curLo + off0);
          Ah1 = *(const bf16x8*)(curHi + off1);
          Al1 = *(const bf16x8*)(curLo + off1);
        }
        __builtin_amdgcn_s_setprio(1);
        C0 = MFMA(Ah0, Wh[0][0], C0, 0, 0, 0);
        C0 = MFMA(Al0, Wh[0][0], C0, 0, 0, 0);
        C0 = MFMA(Ah0, Wl[0][0], C0, 0, 0, 0);
        C0 = MFMA(Ah1, Wh[0][1], C0, 0, 0, 0);
        C0 = MFMA(Al1, Wh[0][1], C0, 0, 0, 0);
        C0 = MFMA(Ah1, Wl[0][1], C0, 0, 0, 0);
        C1 = MFMA(Ah0, Wh[1][0], C1, 0, 0, 0);
        C1 = MFMA(Al0, Wh[1][0], C1, 0, 0, 0);
        C1 = MFMA(Ah0, Wl[1][0], C1, 0, 0, 0);
        C1 = MFMA(Ah1, Wh[1][1], C1, 0, 0, 0);
        C1 = MFMA(Al1, Wh[1][1], C1, 0, 0, 0);
        C1 = MFMA(Ah1, Wl[1][1], C1, 0, 0, 0);
        C2 = MFMA(Ah0, Wh[2][0], C2, 0, 0, 0);
        C2 = MFMA(Al0, Wh[2][0], C2, 0, 0, 0);
        C2 = MFMA(Ah0, Wl[2][0], C2, 0, 0, 0);
        C2 = MFMA(Ah1, Wh[2][1], C2, 0, 0, 0);
        C2 = MFMA(Al1, Wh[2][1], C2, 0, 0, 0);
        C2 = MFMA(Ah1, Wl[2][1], C2, 0, 0, 0);
        C3 = MFMA(Ah0, Wh[3][0], C3, 0, 0, 0);
        C3 = MFMA(Al0, Wh[3][0], C3, 0, 0, 0);
        C3 = MFMA(Ah0, Wl[3][0], C3, 0, 0, 0);
        C3 = MFMA(Ah1, Wh[3][1], C3, 0, 0, 0);
        C3 = MFMA(Al1, Wh[3][1], C3, 0, 0, 0);
        C3 = MFMA(Ah1, Wl[3][1], C3, 0, 0, 0);
        __builtin_amdgcn_s_setprio(0);
        #pragma unroll
        for (int rr = 0; rr < 4; ++rr) {
          float z  = RCP(1.0f + EXP2(-C0[rr]));
          float rg = RCP(1.0f + EXP2(-C1[rr]));
          float y  = C2[rr] + rg * C3[rr];
          float cand = 1.0f - 2.0f * RCP(EXP2(y) + 1.0f);
          float hv = cand + z * (hold[mtl * 4 + rr] - cand);
          hold[mtl * 4 + rr] = hv;
          int off = (((mtg * 2 + ksw) * 4 + gw) * 16 + (g * 4 + rr)) * 8 + jw;
          unsigned u = __float_as_uint(hv);
          float lov = hv - truncbf(hv);
          nxtHi[off] = (unsigned short)(u >> 16);
          nxtLo[off] = (unsigned short)(__float_as_uint(lov) >> 16);
        }
      }
    };

    if (w < 4) {
      do_logits();
      if (s < 24) do_gates();
    } else {
      if (s < 24) do_gates();
      do_logits();
    }
    if (s < 24) light_barrier();
  }
}

extern "C" void kernel_launch(void* const* d_in, const int* in_sizes, int n_in,
                              void* d_out, int out_size, void* d_ws, size_t ws_size,
                              hipStream_t stream) {
  const float* x   = (const float*)d_in[0];
  const float* H   = (const float*)d_in[1];
  const float* Wk  = (const float*)d_in[2];
  const float* Uk  = (const float*)d_in[3];
  const float* b   = (const float*)d_in[4];
  const float* Wd  = (const float*)d_in[5];
  const float* bd  = (const float*)d_in[6];
  float* out = (float*)d_out;
  (void)d_ws; (void)ws_size; (void)in_sizes; (void)n_in; (void)out_size;

  const int lds = 10752 * 4;  // 43008 B -> 2 blocks/CU (grid-capped at 2)
  hipFuncSetAttribute((const void*)vgru_all,
                      hipFuncAttributeMaxDynamicSharedMemorySize, lds);
  vgru_all<<<dim3(512), dim3(TPB), lds, stream>>>(x, H, Wk, Uk, b, Wd, bd, out);
}

// Round 12
// 160.667 us; speedup vs baseline: 3.1421x; 3.1421x over previous
//
#include <hip/hip_runtime.h>

// VGRUd v12 — wave-autonomous rows, zero barriers in the 25-step loop.
// 256 blocks x 512 thr (8 waves), 128 rows/block, 1 block/CU. LDS 151552 B.
// Wave w owns rows w*16..+16 COMPLETELY: computes all 4 gate col-slices and
//   the full 78-col logits row for its own rows. h lives in a WAVE-PRIVATE
//   LDS slot (pre-split hi/lo bf16 planes, A-frag-ready layout, double-buf).
//   Weights (gates 64 frags, Wd 20 frags) are shared read-only LDS, streamed
//   per step. No inter-wave communication after the prologue -> NO BARRIERS:
//   waves drift in phase, so LDS/MFMA/VALU/trans/store units overlap freely
//   instead of taking turns (v6's serial-sum disease).
// exp2-prescaled weights (z,r x log2e; xh,hh x 2log2e; Wd,bd x log2e).
// 3xbf16 MFMA emulation for gates+logits (hi*hi + lo*hi + hi*lo).
// Step 1 (K=192) fused via 6 staged K=32 chunks (barriers OK, one-time);
//   chunk staging aliases the gate-weight arena (staged after step 1).

typedef short bf16x8 __attribute__((ext_vector_type(8)));
typedef float f32x4 __attribute__((ext_vector_type(4)));

#define TPB 512
#define LOG2E 1.44269504088896f
#define S2E   2.88539008177793f

__device__ __forceinline__ unsigned pack_hi16(float a, float b) {
  return __builtin_amdgcn_perm(__float_as_uint(b), __float_as_uint(a), 0x07060302u);
}
__device__ __forceinline__ float truncbf(float a) {
  return __uint_as_float(__float_as_uint(a) & 0xffff0000u);
}
template <int CTRL>
__device__ __forceinline__ float dppror(float x) {
  return __int_as_float(
      __builtin_amdgcn_update_dpp(0, __float_as_int(x), CTRL, 0xf, 0xf, true));
}
__device__ __forceinline__ void split8(const float f[8], bf16x8& ah, bf16x8& al) {
  uint4 ph, pl;
  ph.x = pack_hi16(f[0], f[1]); ph.y = pack_hi16(f[2], f[3]);
  ph.z = pack_hi16(f[4], f[5]); ph.w = pack_hi16(f[6], f[7]);
  pl.x = pack_hi16(f[0] - truncbf(f[0]), f[1] - truncbf(f[1]));
  pl.y = pack_hi16(f[2] - truncbf(f[2]), f[3] - truncbf(f[3]));
  pl.z = pack_hi16(f[4] - truncbf(f[4]), f[5] - truncbf(f[5]));
  pl.w = pack_hi16(f[6] - truncbf(f[6]), f[7] - truncbf(f[7]));
  ah = __builtin_bit_cast(bf16x8, ph);
  al = __builtin_bit_cast(bf16x8, pl);
}

#define MFMA __builtin_amdgcn_mfma_f32_16x16x32_bf16
#define EXP2 __builtin_amdgcn_exp2f
#define RCP  __builtin_amdgcn_rcpf

__global__ __launch_bounds__(TPB, 2) void vgru_all(
    const float* __restrict__ x, const float* __restrict__ Hin,
    const float* __restrict__ Wk, const float* __restrict__ Uk,
    const float* __restrict__ bias, const float* __restrict__ Wd,
    const float* __restrict__ bd, float* __restrict__ out)
{
  extern __shared__ float smem[];
  // floats: gateHi [0,8192) | gateLo [8192,16384) | wdHi [16384,18944)
  //         wdLo [18944,21504) | h slots [21504,37888) (32768 ush)
  // step-1 transient: chkHi [0,4096), chkLo [4096,8192) (alias gateHi, dead after)
  float* chkHi = smem;
  float* chkLo = smem + 4096;
  unsigned short* hs = (unsigned short*)(smem + 21504);
  // wave w, buf p: hs + w*4096 + p*2048; hi [0,1024) ush, lo [1024,2048)
  // element (ks,gk,row,j): ((ks*4+gk)*16+row)*8+j, col = ks*32+gk*8+j

  const int tid  = threadIdx.x;
  const int lane = tid & 63, w = tid >> 6;   // w in 0..7
  const int g = lane >> 4, n = lane & 15;
  const int blockbase = blockIdx.x * 128;
  const int myrow0 = blockbase + w * 16;     // this wave's global rows
  const float* b0 = bias;
  const float* b1 = bias + 192;

  // biases bb[gate][jt] at col jt*16+n (prescaled); bdv[nt]
  float bb[16];
  #pragma unroll
  for (int jt = 0; jt < 4; ++jt) {
    int c = jt * 16 + n;
    bb[0 * 4 + jt] = (b0[c] + b1[c]) * LOG2E;
    bb[1 * 4 + jt] = (b0[64 + c] + b1[64 + c]) * LOG2E;
    bb[2 * 4 + jt] = b0[128 + c] * S2E;
    bb[3 * 4 + jt] = b1[128 + c] * S2E;
  }
  float bdv[5];
  #pragma unroll
  for (int nt = 0; nt < 5; ++nt) {
    int c = nt * 16 + n;
    bdv[nt] = (c < 78) ? bd[c] * LOG2E : 0.0f;
  }

  // ---- step 1: h1 = gru(x, H) for my 16 rows, K=192 in 6 chunks ----
  f32x4 G0[16];  // [ntb = gate*4+jt]
  #pragma unroll
  for (int ntb = 0; ntb < 16; ++ntb) {
    float bv = bb[ntb];
    G0[ntb] = (f32x4){bv, bv, bv, bv};
  }

  for (int t = 0; t < 6; ++t) {
    for (int idx = tid; idx < 1024; idx += TPB) {
      int fr = idx >> 6, ln = idx & 63;      // fr = col-tile ntb 0..15
      int lg = ln >> 4, lnn = ln & 15;
      int c = fr * 16 + lnn;
      float scale = (c < 128) ? LOG2E : S2E;
      float f[8];
      #pragma unroll
      for (int j = 0; j < 8; ++j) {
        int k = t * 32 + lg * 8 + j;
        float v;
        if (k < 128) v = (c < 192) ? Wk[k * 192 + c] : 0.0f;
        else {
          int ku = k - 128;
          v = (c < 128) ? Uk[ku * 192 + c]
                        : ((c < 192) ? 0.0f : Uk[ku * 192 + 128 + (c - 192)]);
        }
        f[j] = v * scale;
      }
      bf16x8 h8, l8; split8(f, h8, l8);
      ((bf16x8*)chkHi)[fr * 64 + ln] = h8;
      ((bf16x8*)chkLo)[fr * 64 + ln] = l8;
    }
    __syncthreads();
    {
      bf16x8 Ah, Al;
      {
        int row = myrow0 + n;
        const float* src = (t < 4)
            ? x + (size_t)row * 128 + t * 32 + g * 8
            : Hin + (size_t)row * 64 + (t - 4) * 32 + g * 8;
        float4 v0 = *(const float4*)src;
        float4 v1 = *(const float4*)(src + 4);
        float f[8] = {v0.x, v0.y, v0.z, v0.w, v1.x, v1.y, v1.z, v1.w};
        split8(f, Ah, Al);
      }
      __builtin_amdgcn_s_setprio(1);
      #pragma unroll
      for (int ntb = 0; ntb < 16; ++ntb) {
        bf16x8 wh = ((const bf16x8*)chkHi)[ntb * 64 + lane];
        bf16x8 wl = ((const bf16x8*)chkLo)[ntb * 64 + lane];
        G0[ntb] = MFMA(Ah, wh, G0[ntb], 0, 0, 0);
        G0[ntb] = MFMA(Al, wh, G0[ntb], 0, 0, 0);
        G0[ntb] = MFMA(Ah, wl, G0[ntb], 0, 0, 0);
      }
      __builtin_amdgcn_s_setprio(0);
    }
    __syncthreads();
  }

  // step-1 epilogue -> hold regs + pre-split h1 into my buf0 slot
  float hold[16];  // [jt*4+rr]
  {
    unsigned short* h0Hi = hs + w * 4096;
    unsigned short* h0Lo = h0Hi + 1024;
    #pragma unroll
    for (int jt = 0; jt < 4; ++jt) {
      const int ksw = jt >> 1;
      const int gkw = (jt & 1) * 2 + (n >> 3);
      const int jw  = n & 7;
      #pragma unroll
      for (int rr = 0; rr < 4; ++rr) {
        int lrow = g * 4 + rr;
        float h0 = Hin[(size_t)(myrow0 + lrow) * 64 + jt * 16 + n];
        float z  = RCP(1.0f + EXP2(-G0[0 * 4 + jt][rr]));
        float rg = RCP(1.0f + EXP2(-G0[1 * 4 + jt][rr]));
        float y  = G0[2 * 4 + jt][rr] + rg * G0[3 * 4 + jt][rr];
        float cand = 1.0f - 2.0f * RCP(EXP2(y) + 1.0f);
        float hv = cand + z * (h0 - cand);
        hold[jt * 4 + rr] = hv;
        int off = ((ksw * 4 + gkw) * 16 + lrow) * 8 + jw;
        unsigned u = __float_as_uint(hv);
        float lov = hv - truncbf(hv);
        h0Hi[off] = (unsigned short)(u >> 16);
        h0Lo[off] = (unsigned short)(__float_as_uint(lov) >> 16);
      }
    }
  }
  __syncthreads();  // all chk reads done -> safe to overwrite with gate arena

  // ---- stage main-loop weights (shared, read-only afterwards) ----
  // gates: 32 frag-pairs [ntb][ks], combined Wk64+Uk, prescaled, split
  for (int idx = tid; idx < 2048; idx += TPB) {
    int fi = idx >> 6, ln = idx & 63;        // fi = ntb*2+ks
    int ntb = fi >> 1, ks = fi & 1;
    int lg = ln >> 4, lnn = ln & 15;
    int c = ntb * 16 + lnn;
    float scale = (c < 128) ? LOG2E : S2E;
    float f[8];
    #pragma unroll
    for (int j = 0; j < 8; ++j) {
      int k = ks * 32 + lg * 8 + j;
      float v;
      if      (c < 128) v = Wk[k * 192 + c] + Uk[k * 192 + c];
      else if (c < 192) v = Wk[k * 192 + c];
      else              v = Uk[k * 192 + 128 + (c - 192)];
      f[j] = v * scale;
    }
    bf16x8 h8, l8; split8(f, h8, l8);
    ((bf16x8*)smem)[fi * 64 + ln] = h8;             // gateHi
    ((bf16x8*)(smem + 8192))[fi * 64 + ln] = l8;    // gateLo
  }
  // wd: 10 frag-pairs [nt][ks], prescaled
  for (int idx = tid; idx < 640; idx += TPB) {
    int fi = idx >> 6, ln = idx & 63;
    int nt = fi >> 1, ks = fi & 1;
    int lg = ln >> 4, lnn = ln & 15;
    int c = nt * 16 + lnn;
    float f[8];
    #pragma unroll
    for (int j = 0; j < 8; ++j) {
      int k = ks * 32 + lg * 8 + j;
      f[j] = (c < 78) ? Wd[k * 78 + c] * LOG2E : 0.0f;
    }
    bf16x8 h8, l8; split8(f, h8, l8);
    ((bf16x8*)(smem + 16384))[fi * 64 + ln] = h8;   // wdHi
    ((bf16x8*)(smem + 18944))[fi * 64 + ln] = l8;   // wdLo
  }
  __syncthreads();  // LAST barrier of the kernel

  const bf16x8* GH  = (const bf16x8*)smem;
  const bf16x8* GL  = (const bf16x8*)(smem + 8192);
  const bf16x8* WDH = (const bf16x8*)(smem + 16384);
  const bf16x8* WDL = (const bf16x8*)(smem + 18944);

  // ---- 25 iterations, barrier-free ----
  #pragma unroll 1
  for (int s = 0; s < 25; ++s) {
    const unsigned short* curHi = hs + w * 4096 + (s & 1) * 2048;
    const unsigned short* curLo = curHi + 1024;
    unsigned short* nxtHi = hs + w * 4096 + ((s + 1) & 1) * 2048;
    unsigned short* nxtLo = nxtHi + 1024;

    // read my A-frags once; reused by logits AND gates
    bf16x8 Ah[2], Al[2];
    #pragma unroll
    for (int ks = 0; ks < 2; ++ks) {
      int off = ((ks * 4 + g) * 16 + n) * 8;
      Ah[ks] = *(const bf16x8*)(curHi + off);
      Al[ks] = *(const bf16x8*)(curLo + off);
    }

    {  // logits (3-term) + softmax + store, my 16 rows
      f32x4 L[5];
      #pragma unroll
      for (int nt = 0; nt < 5; ++nt)
        L[nt] = (f32x4){bdv[nt], bdv[nt], bdv[nt], bdv[nt]};
      __builtin_amdgcn_s_setprio(1);
      #pragma unroll
      for (int nt = 0; nt < 5; ++nt)
        #pragma unroll
        for (int ks = 0; ks < 2; ++ks) {
          bf16x8 wh = WDH[(nt * 2 + ks) * 64 + lane];
          bf16x8 wl = WDL[(nt * 2 + ks) * 64 + lane];
          L[nt] = MFMA(Ah[ks], wh, L[nt], 0, 0, 0);
          L[nt] = MFMA(Al[ks], wh, L[nt], 0, 0, 0);
          L[nt] = MFMA(Ah[ks], wl, L[nt], 0, 0, 0);
        }
      __builtin_amdgcn_s_setprio(0);
      #pragma unroll
      for (int rr = 0; rr < 4; ++rr) {
        float e0 = EXP2(L[0][rr]);
        float e1 = EXP2(L[1][rr]);
        float e2 = EXP2(L[2][rr]);
        float e3 = EXP2(L[3][rr]);
        float e4 = (n < 14) ? EXP2(L[4][rr]) : 0.0f;
        float sm = e0 + e1 + e2 + e3 + e4;
        sm += dppror<0x128>(sm);
        sm += dppror<0x124>(sm);
        sm += dppror<0x122>(sm);
        sm += dppror<0x121>(sm);
        float inv = RCP(sm);
        size_t grow = (size_t)myrow0 + g * 4 + rr;
        float* orow = out + (grow * 25 + s) * 78;
        orow[n]      = e0 * inv;
        orow[16 + n] = e1 * inv;
        orow[32 + n] = e2 * inv;
        orow[48 + n] = e3 * inv;
        if (n < 14) orow[64 + n] = e4 * inv;
      }
    }

    if (s < 24) {
      // gates: my 16 rows, all 4 col-slices
      #pragma unroll
      for (int jt = 0; jt < 4; ++jt) {
        f32x4 C0 = {bb[0*4+jt], bb[0*4+jt], bb[0*4+jt], bb[0*4+jt]};
        f32x4 C1 = {bb[1*4+jt], bb[1*4+jt], bb[1*4+jt], bb[1*4+jt]};
        f32x4 C2 = {bb[2*4+jt], bb[2*4+jt], bb[2*4+jt], bb[2*4+jt]};
        f32x4 C3 = {bb[3*4+jt], bb[3*4+jt], bb[3*4+jt], bb[3*4+jt]};
        __builtin_amdgcn_s_setprio(1);
        #pragma unroll
        for (int ks = 0; ks < 2; ++ks) {
          bf16x8 w0h = GH[((0 * 4 + jt) * 2 + ks) * 64 + lane];
          bf16x8 w0l = GL[((0 * 4 + jt) * 2 + ks) * 64 + lane];
          bf16x8 w1h = GH[((1 * 4 + jt) * 2 + ks) * 64 + lane];
          bf16x8 w1l = GL[((1 * 4 + jt) * 2 + ks) * 64 + lane];
          bf16x8 w2h = GH[((2 * 4 + jt) * 2 + ks) * 64 + lane];
          bf16x8 w2l = GL[((2 * 4 + jt) * 2 + ks) * 64 + lane];
          bf16x8 w3h = GH[((3 * 4 + jt) * 2 + ks) * 64 + lane];
          bf16x8 w3l = GL[((3 * 4 + jt) * 2 + ks) * 64 + lane];
          C0 = MFMA(Ah[ks], w0h, C0, 0, 0, 0);
          C0 = MFMA(Al[ks], w0h, C0, 0, 0, 0);
          C0 = MFMA(Ah[ks], w0l, C0, 0, 0, 0);
          C1 = MFMA(Ah[ks], w1h, C1, 0, 0, 0);
          C1 = MFMA(Al[ks], w1h, C1, 0, 0, 0);
          C1 = MFMA(Ah[ks], w1l, C1, 0, 0, 0);
          C2 = MFMA(Ah[ks], w2h, C2, 0, 0, 0);
          C2 = MFMA(Al[ks], w2h, C2, 0, 0, 0);
          C2 = MFMA(Ah[ks], w2l, C2, 0, 0, 0);
          C3 = MFMA(Ah[ks], w3h, C3, 0, 0, 0);
          C3 = MFMA(Al[ks], w3h, C3, 0, 0, 0);
          C3 = MFMA(Ah[ks], w3l, C3, 0, 0, 0);
        }
        __builtin_amdgcn_s_setprio(0);
        const int ksw = jt >> 1;
        const int gkw = (jt & 1) * 2 + (n >> 3);
        const int jw  = n & 7;
        #pragma unroll
        for (int rr = 0; rr < 4; ++rr) {
          float z  = RCP(1.0f + EXP2(-C0[rr]));
          float rg = RCP(1.0f + EXP2(-C1[rr]));
          float y  = C2[rr] + rg * C3[rr];
          float cand = 1.0f - 2.0f * RCP(EXP2(y) + 1.0f);
          float hv = cand + z * (hold[jt * 4 + rr] - cand);
          hold[jt * 4 + rr] = hv;
          int off = ((ksw * 4 + gkw) * 16 + (g * 4 + rr)) * 8 + jw;
          unsigned u = __float_as_uint(hv);
          float lov = hv - truncbf(hv);
          nxtHi[off] = (unsigned short)(u >> 16);
          nxtLo[off] = (unsigned short)(__float_as_uint(lov) >> 16);
        }
      }
    }
  }
}

extern "C" void kernel_launch(void* const* d_in, const int* in_sizes, int n_in,
                              void* d_out, int out_size, void* d_ws, size_t ws_size,
                              hipStream_t stream) {
  const float* x   = (const float*)d_in[0];
  const float* H   = (const float*)d_in[1];
  const float* Wk  = (const float*)d_in[2];
  const float* Uk  = (const float*)d_in[3];
  const float* b   = (const float*)d_in[4];
  const float* Wd  = (const float*)d_in[5];
  const float* bd  = (const float*)d_in[6];
  float* out = (float*)d_out;
  (void)d_ws; (void)ws_size; (void)in_sizes; (void)n_in; (void)out_size;

  const int lds = 37888 * 4;  // 151552 B -> 1 block/CU
  hipFuncSetAttribute((const void*)vgru_all,
                      hipFuncAttributeMaxDynamicSharedMemorySize, lds);
  vgru_all<<<dim3(256), dim3(TPB), lds, stream>>>(x, H, Wk, Uk, b, Wd, bd, out);
}

// Round 13
// 151.961 us; speedup vs baseline: 3.3221x; 1.0573x over previous
//
#include <hip/hip_runtime.h>

// VGRUd v13 — v12 (wave-autonomous, barrier-free) + restructured step pipeline.
// 256 blocks x 512 thr (8 waves), 128 rows/block, 1 block/CU. LDS 151552 B.
// Wave w owns rows w*16..+16 completely; h in wave-private LDS slot
//   (pre-split hi/lo bf16 planes, A-frag layout, double-buffered).
// Per-step order (the change vs v12):
//   1) gates MFMA (16 accums co-live)  2) logits MFMA (5 accums)
//   3) gate epilogue + h-writes        4) ISSUE next-step A-frag reads
//   5) softmax + probs stores  <- covers the h-write->A-read LDS round trip
// One setprio(1/0) around the whole MFMA region; no barriers in the loop.
// exp2-prescaled weights; trunc lo-split; 3xbf16 MFMA emulation.

typedef short bf16x8 __attribute__((ext_vector_type(8)));
typedef float f32x4 __attribute__((ext_vector_type(4)));

#define TPB 512
#define LOG2E 1.44269504088896f
#define S2E   2.88539008177793f

__device__ __forceinline__ unsigned pack_hi16(float a, float b) {
  return __builtin_amdgcn_perm(__float_as_uint(b), __float_as_uint(a), 0x07060302u);
}
__device__ __forceinline__ float truncbf(float a) {
  return __uint_as_float(__float_as_uint(a) & 0xffff0000u);
}
template <int CTRL>
__device__ __forceinline__ float dppror(float x) {
  return __int_as_float(
      __builtin_amdgcn_update_dpp(0, __float_as_int(x), CTRL, 0xf, 0xf, true));
}
__device__ __forceinline__ void split8(const float f[8], bf16x8& ah, bf16x8& al) {
  uint4 ph, pl;
  ph.x = pack_hi16(f[0], f[1]); ph.y = pack_hi16(f[2], f[3]);
  ph.z = pack_hi16(f[4], f[5]); ph.w = pack_hi16(f[6], f[7]);
  pl.x = pack_hi16(f[0] - truncbf(f[0]), f[1] - truncbf(f[1]));
  pl.y = pack_hi16(f[2] - truncbf(f[2]), f[3] - truncbf(f[3]));
  pl.z = pack_hi16(f[4] - truncbf(f[4]), f[5] - truncbf(f[5]));
  pl.w = pack_hi16(f[6] - truncbf(f[6]), f[7] - truncbf(f[7]));
  ah = __builtin_bit_cast(bf16x8, ph);
  al = __builtin_bit_cast(bf16x8, pl);
}

#define MFMA __builtin_amdgcn_mfma_f32_16x16x32_bf16
#define EXP2 __builtin_amdgcn_exp2f
#define RCP  __builtin_amdgcn_rcpf

__global__ __launch_bounds__(TPB, 2) void vgru_all(
    const float* __restrict__ x, const float* __restrict__ Hin,
    const float* __restrict__ Wk, const float* __restrict__ Uk,
    const float* __restrict__ bias, const float* __restrict__ Wd,
    const float* __restrict__ bd, float* __restrict__ out)
{
  extern __shared__ float smem[];
  // floats: gateHi [0,8192) | gateLo [8192,16384) | wdHi [16384,18944)
  //         wdLo [18944,21504) | h slots [21504,37888) (32768 ush)
  // step-1 transient: chkHi [0,4096), chkLo [4096,8192) (alias gateHi)
  float* chkHi = smem;
  float* chkLo = smem + 4096;
  unsigned short* hs = (unsigned short*)(smem + 21504);
  // wave w, buf p: hs + w*4096 + p*2048; hi [0,1024) ush, lo [1024,2048)
  // element (ks,gk,row,j): ((ks*4+gk)*16+row)*8+j, col = ks*32+gk*8+j

  const int tid  = threadIdx.x;
  const int lane = tid & 63, w = tid >> 6;   // w in 0..7
  const int g = lane >> 4, n = lane & 15;
  const int blockbase = blockIdx.x * 128;
  const int myrow0 = blockbase + w * 16;
  const float* b0 = bias;
  const float* b1 = bias + 192;

  // biases bb[gate][jt] at col jt*16+n (prescaled); bdv[nt]
  float bb[16];
  #pragma unroll
  for (int jt = 0; jt < 4; ++jt) {
    int c = jt * 16 + n;
    bb[0 * 4 + jt] = (b0[c] + b1[c]) * LOG2E;
    bb[1 * 4 + jt] = (b0[64 + c] + b1[64 + c]) * LOG2E;
    bb[2 * 4 + jt] = b0[128 + c] * S2E;
    bb[3 * 4 + jt] = b1[128 + c] * S2E;
  }
  float bdv[5];
  #pragma unroll
  for (int nt = 0; nt < 5; ++nt) {
    int c = nt * 16 + n;
    bdv[nt] = (c < 78) ? bd[c] * LOG2E : 0.0f;
  }

  // ---- step 1: h1 = gru(x, H) for my 16 rows, K=192 in 6 chunks ----
  f32x4 G0[16];
  #pragma unroll
  for (int ntb = 0; ntb < 16; ++ntb) {
    float bv = bb[ntb];
    G0[ntb] = (f32x4){bv, bv, bv, bv};
  }

  for (int t = 0; t < 6; ++t) {
    for (int idx = tid; idx < 1024; idx += TPB) {
      int fr = idx >> 6, ln = idx & 63;
      int lg = ln >> 4, lnn = ln & 15;
      int c = fr * 16 + lnn;
      float scale = (c < 128) ? LOG2E : S2E;
      float f[8];
      #pragma unroll
      for (int j = 0; j < 8; ++j) {
        int k = t * 32 + lg * 8 + j;
        float v;
        if (k < 128) v = (c < 192) ? Wk[k * 192 + c] : 0.0f;
        else {
          int ku = k - 128;
          v = (c < 128) ? Uk[ku * 192 + c]
                        : ((c < 192) ? 0.0f : Uk[ku * 192 + 128 + (c - 192)]);
        }
        f[j] = v * scale;
      }
      bf16x8 h8, l8; split8(f, h8, l8);
      ((bf16x8*)chkHi)[fr * 64 + ln] = h8;
      ((bf16x8*)chkLo)[fr * 64 + ln] = l8;
    }
    __syncthreads();
    {
      bf16x8 Ah, Al;
      {
        int row = myrow0 + n;
        const float* src = (t < 4)
            ? x + (size_t)row * 128 + t * 32 + g * 8
            : Hin + (size_t)row * 64 + (t - 4) * 32 + g * 8;
        float4 v0 = *(const float4*)src;
        float4 v1 = *(const float4*)(src + 4);
        float f[8] = {v0.x, v0.y, v0.z, v0.w, v1.x, v1.y, v1.z, v1.w};
        split8(f, Ah, Al);
      }
      __builtin_amdgcn_s_setprio(1);
      #pragma unroll
      for (int ntb = 0; ntb < 16; ++ntb) {
        bf16x8 wh = ((const bf16x8*)chkHi)[ntb * 64 + lane];
        bf16x8 wl = ((const bf16x8*)chkLo)[ntb * 64 + lane];
        G0[ntb] = MFMA(Ah, wh, G0[ntb], 0, 0, 0);
        G0[ntb] = MFMA(Al, wh, G0[ntb], 0, 0, 0);
        G0[ntb] = MFMA(Ah, wl, G0[ntb], 0, 0, 0);
      }
      __builtin_amdgcn_s_setprio(0);
    }
    __syncthreads();
  }

  // step-1 epilogue -> hold regs + pre-split h1 into my buf0 slot
  float hold[16];  // [jt*4+rr]
  {
    unsigned short* h0Hi = hs + w * 4096;
    unsigned short* h0Lo = h0Hi + 1024;
    #pragma unroll
    for (int jt = 0; jt < 4; ++jt) {
      const int ksw = jt >> 1;
      const int gkw = (jt & 1) * 2 + (n >> 3);
      const int jw  = n & 7;
      #pragma unroll
      for (int rr = 0; rr < 4; ++rr) {
        int lrow = g * 4 + rr;
        float h0 = Hin[(size_t)(myrow0 + lrow) * 64 + jt * 16 + n];
        float z  = RCP(1.0f + EXP2(-G0[0 * 4 + jt][rr]));
        float rg = RCP(1.0f + EXP2(-G0[1 * 4 + jt][rr]));
        float y  = G0[2 * 4 + jt][rr] + rg * G0[3 * 4 + jt][rr];
        float cand = 1.0f - 2.0f * RCP(EXP2(y) + 1.0f);
        float hv = cand + z * (h0 - cand);
        hold[jt * 4 + rr] = hv;
        int off = ((ksw * 4 + gkw) * 16 + lrow) * 8 + jw;
        unsigned u = __float_as_uint(hv);
        float lov = hv - truncbf(hv);
        h0Hi[off] = (unsigned short)(u >> 16);
        h0Lo[off] = (unsigned short)(__float_as_uint(lov) >> 16);
      }
    }
  }
  __syncthreads();  // chk reads done -> safe to overwrite with weight arenas

  // ---- stage main-loop weights (shared, read-only afterwards) ----
  for (int idx = tid; idx < 2048; idx += TPB) {
    int fi = idx >> 6, ln = idx & 63;        // fi = ntb*2+ks
    int ntb = fi >> 1, ks = fi & 1;
    int lg = ln >> 4, lnn = ln & 15;
    int c = ntb * 16 + lnn;
    float scale = (c < 128) ? LOG2E : S2E;
    float f[8];
    #pragma unroll
    for (int j = 0; j < 8; ++j) {
      int k = ks * 32 + lg * 8 + j;
      float v;
      if      (c < 128) v = Wk[k * 192 + c] + Uk[k * 192 + c];
      else if (c < 192) v = Wk[k * 192 + c];
      else              v = Uk[k * 192 + 128 + (c - 192)];
      f[j] = v * scale;
    }
    bf16x8 h8, l8; split8(f, h8, l8);
    ((bf16x8*)smem)[fi * 64 + ln] = h8;             // gateHi
    ((bf16x8*)(smem + 8192))[fi * 64 + ln] = l8;    // gateLo
  }
  for (int idx = tid; idx < 640; idx += TPB) {
    int fi = idx >> 6, ln = idx & 63;
    int nt = fi >> 1, ks = fi & 1;
    int lg = ln >> 4, lnn = ln & 15;
    int c = nt * 16 + lnn;
    float f[8];
    #pragma unroll
    for (int j = 0; j < 8; ++j) {
      int k = ks * 32 + lg * 8 + j;
      f[j] = (c < 78) ? Wd[k * 78 + c] * LOG2E : 0.0f;
    }
    bf16x8 h8, l8; split8(f, h8, l8);
    ((bf16x8*)(smem + 16384))[fi * 64 + ln] = h8;   // wdHi
    ((bf16x8*)(smem + 18944))[fi * 64 + ln] = l8;   // wdLo
  }
  __syncthreads();  // LAST barrier of the kernel

  const bf16x8* GH  = (const bf16x8*)smem;
  const bf16x8* GL  = (const bf16x8*)(smem + 8192);
  const bf16x8* WDH = (const bf16x8*)(smem + 16384);
  const bf16x8* WDL = (const bf16x8*)(smem + 18944);

  // prologue A-frag read from buf0
  bf16x8 Ah[2], Al[2];
  {
    const unsigned short* c0Hi = hs + w * 4096;
    const unsigned short* c0Lo = c0Hi + 1024;
    #pragma unroll
    for (int ks = 0; ks < 2; ++ks) {
      int off = ((ks * 4 + g) * 16 + n) * 8;
      Ah[ks] = *(const bf16x8*)(c0Hi + off);
      Al[ks] = *(const bf16x8*)(c0Lo + off);
    }
  }

  // ---- 25 iterations, barrier-free, pipelined ----
  #pragma unroll 1
  for (int s = 0; s < 25; ++s) {
    unsigned short* nxtHi = hs + w * 4096 + ((s + 1) & 1) * 2048;
    unsigned short* nxtLo = nxtHi + 1024;
    const bool last = (s == 24);

    // ---- MFMA region: gates first (critical path), then logits ----
    f32x4 C[4][4];   // [jt][gate]
    #pragma unroll
    for (int jt = 0; jt < 4; ++jt)
      #pragma unroll
      for (int gg = 0; gg < 4; ++gg) {
        float bv = bb[gg * 4 + jt];
        C[jt][gg] = (f32x4){bv, bv, bv, bv};
      }
    f32x4 L[5];
    #pragma unroll
    for (int nt = 0; nt < 5; ++nt)
      L[nt] = (f32x4){bdv[nt], bdv[nt], bdv[nt], bdv[nt]};

    __builtin_amdgcn_s_setprio(1);
    if (!last) {
      #pragma unroll
      for (int jt = 0; jt < 4; ++jt)
        #pragma unroll
        for (int ks = 0; ks < 2; ++ks) {
          bf16x8 w0h = GH[((0 * 4 + jt) * 2 + ks) * 64 + lane];
          bf16x8 w0l = GL[((0 * 4 + jt) * 2 + ks) * 64 + lane];
          bf16x8 w1h = GH[((1 * 4 + jt) * 2 + ks) * 64 + lane];
          bf16x8 w1l = GL[((1 * 4 + jt) * 2 + ks) * 64 + lane];
          bf16x8 w2h = GH[((2 * 4 + jt) * 2 + ks) * 64 + lane];
          bf16x8 w2l = GL[((2 * 4 + jt) * 2 + ks) * 64 + lane];
          bf16x8 w3h = GH[((3 * 4 + jt) * 2 + ks) * 64 + lane];
          bf16x8 w3l = GL[((3 * 4 + jt) * 2 + ks) * 64 + lane];
          C[jt][0] = MFMA(Ah[ks], w0h, C[jt][0], 0, 0, 0);
          C[jt][0] = MFMA(Al[ks], w0h, C[jt][0], 0, 0, 0);
          C[jt][0] = MFMA(Ah[ks], w0l, C[jt][0], 0, 0, 0);
          C[jt][1] = MFMA(Ah[ks], w1h, C[jt][1], 0, 0, 0);
          C[jt][1] = MFMA(Al[ks], w1h, C[jt][1], 0, 0, 0);
          C[jt][1] = MFMA(Ah[ks], w1l, C[jt][1], 0, 0, 0);
          C[jt][2] = MFMA(Ah[ks], w2h, C[jt][2], 0, 0, 0);
          C[jt][2] = MFMA(Al[ks], w2h, C[jt][2], 0, 0, 0);
          C[jt][2] = MFMA(Ah[ks], w2l, C[jt][2], 0, 0, 0);
          C[jt][3] = MFMA(Ah[ks], w3h, C[jt][3], 0, 0, 0);
          C[jt][3] = MFMA(Al[ks], w3h, C[jt][3], 0, 0, 0);
          C[jt][3] = MFMA(Ah[ks], w3l, C[jt][3], 0, 0, 0);
        }
    }
    #pragma unroll
    for (int nt = 0; nt < 5; ++nt)
      #pragma unroll
      for (int ks = 0; ks < 2; ++ks) {
        bf16x8 wh = WDH[(nt * 2 + ks) * 64 + lane];
        bf16x8 wl = WDL[(nt * 2 + ks) * 64 + lane];
        L[nt] = MFMA(Ah[ks], wh, L[nt], 0, 0, 0);
        L[nt] = MFMA(Al[ks], wh, L[nt], 0, 0, 0);
        L[nt] = MFMA(Ah[ks], wl, L[nt], 0, 0, 0);
      }
    __builtin_amdgcn_s_setprio(0);

    // ---- gate epilogue + h-writes (critical path), then A-prefetch ----
    if (!last) {
      #pragma unroll
      for (int jt = 0; jt < 4; ++jt) {
        const int ksw = jt >> 1;
        const int gkw = (jt & 1) * 2 + (n >> 3);
        const int jw  = n & 7;
        #pragma unroll
        for (int rr = 0; rr < 4; ++rr) {
          float z  = RCP(1.0f + EXP2(-C[jt][0][rr]));
          float rg = RCP(1.0f + EXP2(-C[jt][1][rr]));
          float y  = C[jt][2][rr] + rg * C[jt][3][rr];
          float cand = 1.0f - 2.0f * RCP(EXP2(y) + 1.0f);
          float hv = cand + z * (hold[jt * 4 + rr] - cand);
          hold[jt * 4 + rr] = hv;
          int off = ((ksw * 4 + gkw) * 16 + (g * 4 + rr)) * 8 + jw;
          unsigned u = __float_as_uint(hv);
          float lov = hv - truncbf(hv);
          nxtHi[off] = (unsigned short)(u >> 16);
          nxtLo[off] = (unsigned short)(__float_as_uint(lov) >> 16);
        }
      }
      // issue next-step A-frag reads NOW (same-wave DS ops are in-order, so
      // these see the writes above); latency hides under softmax below.
      #pragma unroll
      for (int ks = 0; ks < 2; ++ks) {
        int off = ((ks * 4 + g) * 16 + n) * 8;
        Ah[ks] = *(const bf16x8*)(nxtHi + off);
        Al[ks] = *(const bf16x8*)(nxtLo + off);
      }
    }

    // ---- softmax + probs stores (off the critical path) ----
    #pragma unroll
    for (int rr = 0; rr < 4; ++rr) {
      float e0 = EXP2(L[0][rr]);
      float e1 = EXP2(L[1][rr]);
      float e2 = EXP2(L[2][rr]);
      float e3 = EXP2(L[3][rr]);
      float e4 = (n < 14) ? EXP2(L[4][rr]) : 0.0f;
      float sm = e0 + e1 + e2 + e3 + e4;
      sm += dppror<0x128>(sm);
      sm += dppror<0x124>(sm);
      sm += dppror<0x122>(sm);
      sm += dppror<0x121>(sm);
      float inv = RCP(sm);
      size_t grow = (size_t)myrow0 + g * 4 + rr;
      float* orow = out + (grow * 25 + s) * 78;
      orow[n]      = e0 * inv;
      orow[16 + n] = e1 * inv;
      orow[32 + n] = e2 * inv;
      orow[48 + n] = e3 * inv;
      if (n < 14) orow[64 + n] = e4 * inv;
    }
  }
}

extern "C" void kernel_launch(void* const* d_in, const int* in_sizes, int n_in,
                              void* d_out, int out_size, void* d_ws, size_t ws_size,
                              hipStream_t stream) {
  const float* x   = (const float*)d_in[0];
  const float* H   = (const float*)d_in[1];
  const float* Wk  = (const float*)d_in[2];
  const float* Uk  = (const float*)d_in[3];
  const float* b   = (const float*)d_in[4];
  const float* Wd  = (const float*)d_in[5];
  const float* bd  = (const float*)d_in[6];
  float* out = (float*)d_out;
  (void)d_ws; (void)ws_size; (void)in_sizes; (void)n_in; (void)out_size;

  const int lds = 37888 * 4;  // 151552 B -> 1 block/CU
  hipFuncSetAttribute((const void*)vgru_all,
                      hipFuncAttributeMaxDynamicSharedMemorySize, lds);
  vgru_all<<<dim3(256), dim3(TPB), lds, stream>>>(x, H, Wk, Uk, b, Wd, bd, out);
}

// Round 14
// 129.333 us; speedup vs baseline: 3.9034x; 1.1750x over previous
//
#include <hip/hip_runtime.h>

// VGRUd v14 — v13 structure with f16 single-plane weights + f16 hi/lo h.
// 256 blocks x 512 thr (8 waves), 128 rows/block, 1 block/CU. LDS 108544 B.
// Wave w owns rows w*16..+16 completely (autonomous, NO barriers in loop).
// Numerics: weights (gates+Wd) stored as ONE f16 plane (prescaled by log2e /
//   2log2e); h stored as f16 hi + f16 lo (residual) -> preact = (Ah+Al)*W:
//   2 MFMA per term-group instead of 3, half the weight LDS stream.
// Per-step/wave: 46 ds_read_b128 (was 88), 84 MFMA (was 126).
// Pipeline per step: gates MFMA -> logits MFMA -> gate epilogue + h-writes ->
//   next-step A-frag prefetch -> softmax + probs stores (covers LDS roundtrip).

typedef _Float16 f16x8 __attribute__((ext_vector_type(8)));
typedef float f32x4 __attribute__((ext_vector_type(4)));

#define TPB 512
#define LOG2E 1.44269504088896f
#define S2E   2.88539008177793f

template <int CTRL>
__device__ __forceinline__ float dppror(float x) {
  return __int_as_float(
      __builtin_amdgcn_update_dpp(0, __float_as_int(x), CTRL, 0xf, 0xf, true));
}
__device__ __forceinline__ void split8h(const float f[8], f16x8& hi, f16x8& lo) {
  #pragma unroll
  for (int j = 0; j < 8; ++j) {
    _Float16 h = (_Float16)f[j];
    hi[j] = h;
    lo[j] = (_Float16)(f[j] - (float)h);
  }
}

#define MFMA __builtin_amdgcn_mfma_f32_16x16x32_f16
#define EXP2 __builtin_amdgcn_exp2f
#define RCP  __builtin_amdgcn_rcpf

__global__ __launch_bounds__(TPB, 2) void vgru_all(
    const float* __restrict__ x, const float* __restrict__ Hin,
    const float* __restrict__ Wk, const float* __restrict__ Uk,
    const float* __restrict__ bias, const float* __restrict__ Wd,
    const float* __restrict__ bd, float* __restrict__ out)
{
  extern __shared__ float smem[];
  // floats: gateW [0,8192) (32 frags) | wd [8192,10752) (10 frags)
  //         h slots [10752,27136) = 32768 ush
  // step-1 transient: chkW [0,4096) (16 frags), aliases gateW (staged after).
  float* chkW = smem;
  unsigned short* hs = (unsigned short*)(smem + 10752);
  // wave w, buf p: hs + w*4096 + p*2048; hi [0,1024) ush, lo [1024,2048)
  // element (ks,gk,row,j): ((ks*4+gk)*16+row)*8+j, col = ks*32+gk*8+j

  const int tid  = threadIdx.x;
  const int lane = tid & 63, w = tid >> 6;   // w in 0..7
  const int g = lane >> 4, n = lane & 15;
  const int blockbase = blockIdx.x * 128;
  const int myrow0 = blockbase + w * 16;
  const float* b0 = bias;
  const float* b1 = bias + 192;

  // biases bb[gate*4+jt] at col jt*16+n (prescaled); bdv[nt]
  float bb[16];
  #pragma unroll
  for (int jt = 0; jt < 4; ++jt) {
    int c = jt * 16 + n;
    bb[0 * 4 + jt] = (b0[c] + b1[c]) * LOG2E;
    bb[1 * 4 + jt] = (b0[64 + c] + b1[64 + c]) * LOG2E;
    bb[2 * 4 + jt] = b0[128 + c] * S2E;
    bb[3 * 4 + jt] = b1[128 + c] * S2E;
  }
  float bdv[5];
  #pragma unroll
  for (int nt = 0; nt < 5; ++nt) {
    int c = nt * 16 + n;
    bdv[nt] = (c < 78) ? bd[c] * LOG2E : 0.0f;
  }

  // ---- step 1: h1 = gru(x, H) for my 16 rows, K=192 in 6 chunks ----
  f32x4 G0[16];
  #pragma unroll
  for (int ntb = 0; ntb < 16; ++ntb) {
    float bv = bb[ntb];
    G0[ntb] = (f32x4){bv, bv, bv, bv};
  }

  for (int t = 0; t < 6; ++t) {
    for (int idx = tid; idx < 1024; idx += TPB) {
      int fr = idx >> 6, ln = idx & 63;      // fr = col-tile ntb 0..15
      int lg = ln >> 4, lnn = ln & 15;
      int c = fr * 16 + lnn;
      float scale = (c < 128) ? LOG2E : S2E;
      f16x8 wf;
      #pragma unroll
      for (int j = 0; j < 8; ++j) {
        int k = t * 32 + lg * 8 + j;
        float v;
        if (k < 128) v = (c < 192) ? Wk[k * 192 + c] : 0.0f;
        else {
          int ku = k - 128;
          v = (c < 128) ? Uk[ku * 192 + c]
                        : ((c < 192) ? 0.0f : Uk[ku * 192 + 128 + (c - 192)]);
        }
        wf[j] = (_Float16)(v * scale);
      }
      ((f16x8*)chkW)[fr * 64 + ln] = wf;
    }
    __syncthreads();
    {
      f16x8 Ah, Al;
      {
        int row = myrow0 + n;
        const float* src = (t < 4)
            ? x + (size_t)row * 128 + t * 32 + g * 8
            : Hin + (size_t)row * 64 + (t - 4) * 32 + g * 8;
        float4 v0 = *(const float4*)src;
        float4 v1 = *(const float4*)(src + 4);
        float f[8] = {v0.x, v0.y, v0.z, v0.w, v1.x, v1.y, v1.z, v1.w};
        split8h(f, Ah, Al);
      }
      __builtin_amdgcn_s_setprio(1);
      #pragma unroll
      for (int ntb = 0; ntb < 16; ++ntb) {
        f16x8 wf = ((const f16x8*)chkW)[ntb * 64 + lane];
        G0[ntb] = MFMA(Ah, wf, G0[ntb], 0, 0, 0);
        G0[ntb] = MFMA(Al, wf, G0[ntb], 0, 0, 0);
      }
      __builtin_amdgcn_s_setprio(0);
    }
    __syncthreads();
  }

  // step-1 epilogue -> hold regs + f16-pair h1 into my buf0 slot
  float hold[16];  // [jt*4+rr]
  {
    unsigned short* h0Hi = hs + w * 4096;
    unsigned short* h0Lo = h0Hi + 1024;
    #pragma unroll
    for (int jt = 0; jt < 4; ++jt) {
      const int ksw = jt >> 1;
      const int gkw = (jt & 1) * 2 + (n >> 3);
      const int jw  = n & 7;
      #pragma unroll
      for (int rr = 0; rr < 4; ++rr) {
        int lrow = g * 4 + rr;
        float h0 = Hin[(size_t)(myrow0 + lrow) * 64 + jt * 16 + n];
        float z  = RCP(1.0f + EXP2(-G0[0 * 4 + jt][rr]));
        float rg = RCP(1.0f + EXP2(-G0[1 * 4 + jt][rr]));
        float y  = G0[2 * 4 + jt][rr] + rg * G0[3 * 4 + jt][rr];
        float cand = 1.0f - 2.0f * RCP(EXP2(y) + 1.0f);
        float hv = cand + z * (h0 - cand);
        hold[jt * 4 + rr] = hv;
        int off = ((ksw * 4 + gkw) * 16 + lrow) * 8 + jw;
        _Float16 hh = (_Float16)hv;
        _Float16 hl = (_Float16)(hv - (float)hh);
        h0Hi[off] = __builtin_bit_cast(unsigned short, hh);
        h0Lo[off] = __builtin_bit_cast(unsigned short, hl);
      }
    }
  }
  __syncthreads();  // chk reads done -> safe to overwrite with weight arenas

  // ---- stage main-loop weights (shared, read-only afterwards) ----
  // gates: 32 frags [ntb][ks], combined Wk64+Uk, prescaled, f16
  for (int idx = tid; idx < 2048; idx += TPB) {
    int fi = idx >> 6, ln = idx & 63;        // fi = ntb*2+ks
    int ntb = fi >> 1, ks = fi & 1;
    int lg = ln >> 4, lnn = ln & 15;
    int c = ntb * 16 + lnn;
    float scale = (c < 128) ? LOG2E : S2E;
    f16x8 wf;
    #pragma unroll
    for (int j = 0; j < 8; ++j) {
      int k = ks * 32 + lg * 8 + j;
      float v;
      if      (c < 128) v = Wk[k * 192 + c] + Uk[k * 192 + c];
      else if (c < 192) v = Wk[k * 192 + c];
      else              v = Uk[k * 192 + 128 + (c - 192)];
      wf[j] = (_Float16)(v * scale);
    }
    ((f16x8*)smem)[fi * 64 + ln] = wf;              // gateW
  }
  // wd: 10 frags [nt][ks], prescaled, f16
  for (int idx = tid; idx < 640; idx += TPB) {
    int fi = idx >> 6, ln = idx & 63;
    int nt = fi >> 1, ks = fi & 1;
    int lg = ln >> 4, lnn = ln & 15;
    int c = nt * 16 + lnn;
    f16x8 wf;
    #pragma unroll
    for (int j = 0; j < 8; ++j) {
      int k = ks * 32 + lg * 8 + j;
      wf[j] = (_Float16)((c < 78) ? Wd[k * 78 + c] * LOG2E : 0.0f);
    }
    ((f16x8*)(smem + 8192))[fi * 64 + ln] = wf;     // wd
  }
  __syncthreads();  // LAST barrier of the kernel

  const f16x8* GW = (const f16x8*)smem;
  const f16x8* WD = (const f16x8*)(smem + 8192);

  // prologue A-frag read from buf0
  f16x8 Ah[2], Al[2];
  {
    const unsigned short* c0Hi = hs + w * 4096;
    const unsigned short* c0Lo = c0Hi + 1024;
    #pragma unroll
    for (int ks = 0; ks < 2; ++ks) {
      int off = ((ks * 4 + g) * 16 + n) * 8;
      Ah[ks] = *(const f16x8*)(c0Hi + off);
      Al[ks] = *(const f16x8*)(c0Lo + off);
    }
  }

  // ---- 25 iterations, barrier-free, pipelined ----
  #pragma unroll 1
  for (int s = 0; s < 25; ++s) {
    unsigned short* nxtHi = hs + w * 4096 + ((s + 1) & 1) * 2048;
    unsigned short* nxtLo = nxtHi + 1024;
    const bool last = (s == 24);

    // ---- MFMA region: gates first (critical path), then logits ----
    f32x4 C[4][4];   // [jt][gate]
    #pragma unroll
    for (int jt = 0; jt < 4; ++jt)
      #pragma unroll
      for (int gg = 0; gg < 4; ++gg) {
        float bv = bb[gg * 4 + jt];
        C[jt][gg] = (f32x4){bv, bv, bv, bv};
      }
    f32x4 L[5];
    #pragma unroll
    for (int nt = 0; nt < 5; ++nt)
      L[nt] = (f32x4){bdv[nt], bdv[nt], bdv[nt], bdv[nt]};

    __builtin_amdgcn_s_setprio(1);
    if (!last) {
      #pragma unroll
      for (int jt = 0; jt < 4; ++jt)
        #pragma unroll
        for (int ks = 0; ks < 2; ++ks) {
          f16x8 w0 = GW[((0 * 4 + jt) * 2 + ks) * 64 + lane];
          f16x8 w1 = GW[((1 * 4 + jt) * 2 + ks) * 64 + lane];
          f16x8 w2 = GW[((2 * 4 + jt) * 2 + ks) * 64 + lane];
          f16x8 w3 = GW[((3 * 4 + jt) * 2 + ks) * 64 + lane];
          C[jt][0] = MFMA(Ah[ks], w0, C[jt][0], 0, 0, 0);
          C[jt][0] = MFMA(Al[ks], w0, C[jt][0], 0, 0, 0);
          C[jt][1] = MFMA(Ah[ks], w1, C[jt][1], 0, 0, 0);
          C[jt][1] = MFMA(Al[ks], w1, C[jt][1], 0, 0, 0);
          C[jt][2] = MFMA(Ah[ks], w2, C[jt][2], 0, 0, 0);
          C[jt][2] = MFMA(Al[ks], w2, C[jt][2], 0, 0, 0);
          C[jt][3] = MFMA(Ah[ks], w3, C[jt][3], 0, 0, 0);
          C[jt][3] = MFMA(Al[ks], w3, C[jt][3], 0, 0, 0);
        }
    }
    #pragma unroll
    for (int nt = 0; nt < 5; ++nt)
      #pragma unroll
      for (int ks = 0; ks < 2; ++ks) {
        f16x8 wd8 = WD[(nt * 2 + ks) * 64 + lane];
        L[nt] = MFMA(Ah[ks], wd8, L[nt], 0, 0, 0);
        L[nt] = MFMA(Al[ks], wd8, L[nt], 0, 0, 0);
      }
    __builtin_amdgcn_s_setprio(0);

    // ---- gate epilogue + h-writes (critical path), then A-prefetch ----
    if (!last) {
      #pragma unroll
      for (int jt = 0; jt < 4; ++jt) {
        const int ksw = jt >> 1;
        const int gkw = (jt & 1) * 2 + (n >> 3);
        const int jw  = n & 7;
        #pragma unroll
        for (int rr = 0; rr < 4; ++rr) {
          float z  = RCP(1.0f + EXP2(-C[jt][0][rr]));
          float rg = RCP(1.0f + EXP2(-C[jt][1][rr]));
          float y  = C[jt][2][rr] + rg * C[jt][3][rr];
          float cand = 1.0f - 2.0f * RCP(EXP2(y) + 1.0f);
          float hv = cand + z * (hold[jt * 4 + rr] - cand);
          hold[jt * 4 + rr] = hv;
          int off = ((ksw * 4 + gkw) * 16 + (g * 4 + rr)) * 8 + jw;
          _Float16 hh = (_Float16)hv;
          _Float16 hl = (_Float16)(hv - (float)hh);
          nxtHi[off] = __builtin_bit_cast(unsigned short, hh);
          nxtLo[off] = __builtin_bit_cast(unsigned short, hl);
        }
      }
      // next-step A-frag reads (same-wave DS ops in order -> see the writes);
      // latency hides under softmax below.
      #pragma unroll
      for (int ks = 0; ks < 2; ++ks) {
        int off = ((ks * 4 + g) * 16 + n) * 8;
        Ah[ks] = *(const f16x8*)(nxtHi + off);
        Al[ks] = *(const f16x8*)(nxtLo + off);
      }
    }

    // ---- softmax + probs stores (off the critical path) ----
    #pragma unroll
    for (int rr = 0; rr < 4; ++rr) {
      float e0 = EXP2(L[0][rr]);
      float e1 = EXP2(L[1][rr]);
      float e2 = EXP2(L[2][rr]);
      float e3 = EXP2(L[3][rr]);
      float e4 = (n < 14) ? EXP2(L[4][rr]) : 0.0f;
      float sm = e0 + e1 + e2 + e3 + e4;
      sm += dppror<0x128>(sm);
      sm += dppror<0x124>(sm);
      sm += dppror<0x122>(sm);
      sm += dppror<0x121>(sm);
      float inv = RCP(sm);
      size_t grow = (size_t)myrow0 + g * 4 + rr;
      float* orow = out + (grow * 25 + s) * 78;
      orow[n]      = e0 * inv;
      orow[16 + n] = e1 * inv;
      orow[32 + n] = e2 * inv;
      orow[48 + n] = e3 * inv;
      if (n < 14) orow[64 + n] = e4 * inv;
    }
  }
}

extern "C" void kernel_launch(void* const* d_in, const int* in_sizes, int n_in,
                              void* d_out, int out_size, void* d_ws, size_t ws_size,
                              hipStream_t stream) {
  const float* x   = (const float*)d_in[0];
  const float* H   = (const float*)d_in[1];
  const float* Wk  = (const float*)d_in[2];
  const float* Uk  = (const float*)d_in[3];
  const float* b   = (const float*)d_in[4];
  const float* Wd  = (const float*)d_in[5];
  const float* bd  = (const float*)d_in[6];
  float* out = (float*)d_out;
  (void)d_ws; (void)ws_size; (void)in_sizes; (void)n_in; (void)out_size;

  const int lds = 27136 * 4;  // 108544 B -> 1 block/CU
  hipFuncSetAttribute((const void*)vgru_all,
                      hipFuncAttributeMaxDynamicSharedMemorySize, lds);
  vgru_all<<<dim3(256), dim3(TPB), lds, stream>>>(x, H, Wk, Uk, b, Wd, bd, out);
}

// Round 15
// 115.854 us; speedup vs baseline: 4.3575x; 1.1163x over previous
//
#include <hip/hip_runtime.h>

// VGRUd v15 — v14 + single-plane f16 h + persistent Wd registers.
// 256 blocks x 512 thr (8 waves), 128 rows/block, 1 block/CU. LDS 75776 B.
// Wave w owns rows w*16..+16 (autonomous, NO barriers in the 25-step loop).
// Numerics: weights one f16 plane (prescaled log2e / 2log2e). h in LDS as ONE
//   f16 plane — the exact f32 recurrence state lives in `hold` registers, so
//   h-quantization enters only through MFMA A-operands (no compounding).
// Wd frags persistent in VGPR (10 frags = 40 regs) -> logits block reads no LDS.
// Per-step/wave: 34 ds_read_b128 (was 46), 16 ds_write_b16 (was 32), 42 MFMA.
// Pipeline: gates MFMA -> logits MFMA -> gate epilogue + h-writes ->
//   next-step A-prefetch -> softmax + probs stores (covers LDS roundtrip).

typedef _Float16 f16x8 __attribute__((ext_vector_type(8)));
typedef float f32x4 __attribute__((ext_vector_type(4)));

#define TPB 512
#define LOG2E 1.44269504088896f
#define S2E   2.88539008177793f

template <int CTRL>
__device__ __forceinline__ float dppror(float x) {
  return __int_as_float(
      __builtin_amdgcn_update_dpp(0, __float_as_int(x), CTRL, 0xf, 0xf, true));
}
__device__ __forceinline__ void split8h(const float f[8], f16x8& hi, f16x8& lo) {
  #pragma unroll
  for (int j = 0; j < 8; ++j) {
    _Float16 h = (_Float16)f[j];
    hi[j] = h;
    lo[j] = (_Float16)(f[j] - (float)h);
  }
}

#define MFMA __builtin_amdgcn_mfma_f32_16x16x32_f16
#define EXP2 __builtin_amdgcn_exp2f
#define RCP  __builtin_amdgcn_rcpf

__global__ __launch_bounds__(TPB, 2) void vgru_all(
    const float* __restrict__ x, const float* __restrict__ Hin,
    const float* __restrict__ Wk, const float* __restrict__ Uk,
    const float* __restrict__ bias, const float* __restrict__ Wd,
    const float* __restrict__ bd, float* __restrict__ out)
{
  extern __shared__ float smem[];
  // floats: gateW [0,8192) (32 frags f16x8) | wdStage [8192,10752)
  //         h slots [10752,18944) = 16384 ush (8 waves x 2 bufs x 1024 ush)
  // step-1 transient: chkW [0,4096) (16 frags), aliases gateW.
  float* chkW = smem;
  unsigned short* hs = (unsigned short*)(smem + 10752);
  // wave w, buf p: hs + w*2048 + p*1024
  // element (ks,gk,row,j): ((ks*4+gk)*16+row)*8+j, col = ks*32+gk*8+j

  const int tid  = threadIdx.x;
  const int lane = tid & 63, w = tid >> 6;   // w in 0..7
  const int g = lane >> 4, n = lane & 15;
  const int blockbase = blockIdx.x * 128;
  const int myrow0 = blockbase + w * 16;
  const float* b0 = bias;
  const float* b1 = bias + 192;

  // biases bb[gate*4+jt] at col jt*16+n (prescaled); bdv[nt]
  float bb[16];
  #pragma unroll
  for (int jt = 0; jt < 4; ++jt) {
    int c = jt * 16 + n;
    bb[0 * 4 + jt] = (b0[c] + b1[c]) * LOG2E;
    bb[1 * 4 + jt] = (b0[64 + c] + b1[64 + c]) * LOG2E;
    bb[2 * 4 + jt] = b0[128 + c] * S2E;
    bb[3 * 4 + jt] = b1[128 + c] * S2E;
  }
  float bdv[5];
  #pragma unroll
  for (int nt = 0; nt < 5; ++nt) {
    int c = nt * 16 + n;
    bdv[nt] = (c < 78) ? bd[c] * LOG2E : 0.0f;
  }

  // ---- step 1: h1 = gru(x, H) for my 16 rows, K=192 in 6 chunks ----
  // inputs are full f32 -> keep 2-term (Ah+Al)*W here for accuracy
  f32x4 G0[16];
  #pragma unroll
  for (int ntb = 0; ntb < 16; ++ntb) {
    float bv = bb[ntb];
    G0[ntb] = (f32x4){bv, bv, bv, bv};
  }

  for (int t = 0; t < 6; ++t) {
    for (int idx = tid; idx < 1024; idx += TPB) {
      int fr = idx >> 6, ln = idx & 63;      // fr = col-tile ntb 0..15
      int lg = ln >> 4, lnn = ln & 15;
      int c = fr * 16 + lnn;
      float scale = (c < 128) ? LOG2E : S2E;
      f16x8 wf;
      #pragma unroll
      for (int j = 0; j < 8; ++j) {
        int k = t * 32 + lg * 8 + j;
        float v;
        if (k < 128) v = (c < 192) ? Wk[k * 192 + c] : 0.0f;
        else {
          int ku = k - 128;
          v = (c < 128) ? Uk[ku * 192 + c]
                        : ((c < 192) ? 0.0f : Uk[ku * 192 + 128 + (c - 192)]);
        }
        wf[j] = (_Float16)(v * scale);
      }
      ((f16x8*)chkW)[fr * 64 + ln] = wf;
    }
    __syncthreads();
    {
      f16x8 Ah, Al;
      {
        int row = myrow0 + n;
        const float* src = (t < 4)
            ? x + (size_t)row * 128 + t * 32 + g * 8
            : Hin + (size_t)row * 64 + (t - 4) * 32 + g * 8;
        float4 v0 = *(const float4*)src;
        float4 v1 = *(const float4*)(src + 4);
        float f[8] = {v0.x, v0.y, v0.z, v0.w, v1.x, v1.y, v1.z, v1.w};
        split8h(f, Ah, Al);
      }
      __builtin_amdgcn_s_setprio(1);
      #pragma unroll
      for (int ntb = 0; ntb < 16; ++ntb) {
        f16x8 wf = ((const f16x8*)chkW)[ntb * 64 + lane];
        G0[ntb] = MFMA(Ah, wf, G0[ntb], 0, 0, 0);
        G0[ntb] = MFMA(Al, wf, G0[ntb], 0, 0, 0);
      }
      __builtin_amdgcn_s_setprio(0);
    }
    __syncthreads();
  }

  // step-1 epilogue -> hold regs + single-plane f16 h1 into my buf0 slot
  float hold[16];  // [jt*4+rr]
  {
    unsigned short* h0 = hs + w * 2048;
    #pragma unroll
    for (int jt = 0; jt < 4; ++jt) {
      const int ksw = jt >> 1;
      const int gkw = (jt & 1) * 2 + (n >> 3);
      const int jw  = n & 7;
      #pragma unroll
      for (int rr = 0; rr < 4; ++rr) {
        int lrow = g * 4 + rr;
        float h0v = Hin[(size_t)(myrow0 + lrow) * 64 + jt * 16 + n];
        float z  = RCP(1.0f + EXP2(-G0[0 * 4 + jt][rr]));
        float rg = RCP(1.0f + EXP2(-G0[1 * 4 + jt][rr]));
        float y  = G0[2 * 4 + jt][rr] + rg * G0[3 * 4 + jt][rr];
        float cand = 1.0f - 2.0f * RCP(EXP2(y) + 1.0f);
        float hv = cand + z * (h0v - cand);
        hold[jt * 4 + rr] = hv;
        int off = ((ksw * 4 + gkw) * 16 + lrow) * 8 + jw;
        h0[off] = __builtin_bit_cast(unsigned short, (_Float16)hv);
      }
    }
  }
  __syncthreads();  // chk reads done -> safe to overwrite with weight arenas

  // ---- stage main-loop weights ----
  // gates: 32 frags [ntb][ks], combined Wk64+Uk, prescaled, f16 (stay in LDS)
  for (int idx = tid; idx < 2048; idx += TPB) {
    int fi = idx >> 6, ln = idx & 63;        // fi = ntb*2+ks
    int ntb = fi >> 1, ks = fi & 1;
    int lg = ln >> 4, lnn = ln & 15;
    int c = ntb * 16 + lnn;
    float scale = (c < 128) ? LOG2E : S2E;
    f16x8 wf;
    #pragma unroll
    for (int j = 0; j < 8; ++j) {
      int k = ks * 32 + lg * 8 + j;
      float v;
      if      (c < 128) v = Wk[k * 192 + c] + Uk[k * 192 + c];
      else if (c < 192) v = Wk[k * 192 + c];
      else              v = Uk[k * 192 + 128 + (c - 192)];
      wf[j] = (_Float16)(v * scale);
    }
    ((f16x8*)smem)[fi * 64 + ln] = wf;              // gateW
  }
  // wd: stage 10 frags, then each wave loads them into REGISTERS
  for (int idx = tid; idx < 640; idx += TPB) {
    int fi = idx >> 6, ln = idx & 63;
    int nt = fi >> 1, ks = fi & 1;
    int lg = ln >> 4, lnn = ln & 15;
    int c = nt * 16 + lnn;
    f16x8 wf;
    #pragma unroll
    for (int j = 0; j < 8; ++j) {
      int k = ks * 32 + lg * 8 + j;
      wf[j] = (_Float16)((c < 78) ? Wd[k * 78 + c] * LOG2E : 0.0f);
    }
    ((f16x8*)(smem + 8192))[fi * 64 + ln] = wf;     // wdStage
  }
  __syncthreads();  // LAST barrier of the kernel

  const f16x8* GW = (const f16x8*)smem;
  // persistent Wd (10 frags = 40 VGPR)
  f16x8 wdr[5][2];
  #pragma unroll
  for (int nt = 0; nt < 5; ++nt)
    #pragma unroll
    for (int ks = 0; ks < 2; ++ks)
      wdr[nt][ks] = ((const f16x8*)(smem + 8192))[(nt * 2 + ks) * 64 + lane];

  // prologue A-frag read from buf0
  f16x8 Ah[2];
  {
    const unsigned short* c0 = hs + w * 2048;
    #pragma unroll
    for (int ks = 0; ks < 2; ++ks) {
      int off = ((ks * 4 + g) * 16 + n) * 8;
      Ah[ks] = *(const f16x8*)(c0 + off);
    }
  }

  // ---- 25 iterations, barrier-free, pipelined ----
  #pragma unroll 1
  for (int s = 0; s < 25; ++s) {
    unsigned short* nxt = hs + w * 2048 + ((s + 1) & 1) * 1024;
    const bool last = (s == 24);

    // ---- MFMA region: gates first (critical path), then logits ----
    f32x4 C[4][4];   // [jt][gate]
    #pragma unroll
    for (int jt = 0; jt < 4; ++jt)
      #pragma unroll
      for (int gg = 0; gg < 4; ++gg) {
        float bv = bb[gg * 4 + jt];
        C[jt][gg] = (f32x4){bv, bv, bv, bv};
      }
    f32x4 L[5];
    #pragma unroll
    for (int nt = 0; nt < 5; ++nt)
      L[nt] = (f32x4){bdv[nt], bdv[nt], bdv[nt], bdv[nt]};

    __builtin_amdgcn_s_setprio(1);
    if (!last) {
      #pragma unroll
      for (int jt = 0; jt < 4; ++jt)
        #pragma unroll
        for (int ks = 0; ks < 2; ++ks) {
          f16x8 w0 = GW[((0 * 4 + jt) * 2 + ks) * 64 + lane];
          f16x8 w1 = GW[((1 * 4 + jt) * 2 + ks) * 64 + lane];
          f16x8 w2 = GW[((2 * 4 + jt) * 2 + ks) * 64 + lane];
          f16x8 w3 = GW[((3 * 4 + jt) * 2 + ks) * 64 + lane];
          C[jt][0] = MFMA(Ah[ks], w0, C[jt][0], 0, 0, 0);
          C[jt][1] = MFMA(Ah[ks], w1, C[jt][1], 0, 0, 0);
          C[jt][2] = MFMA(Ah[ks], w2, C[jt][2], 0, 0, 0);
          C[jt][3] = MFMA(Ah[ks], w3, C[jt][3], 0, 0, 0);
        }
    }
    #pragma unroll
    for (int nt = 0; nt < 5; ++nt)
      #pragma unroll
      for (int ks = 0; ks < 2; ++ks)
        L[nt] = MFMA(Ah[ks], wdr[nt][ks], L[nt], 0, 0, 0);
    __builtin_amdgcn_s_setprio(0);

    // ---- gate epilogue + h-writes (critical path), then A-prefetch ----
    if (!last) {
      #pragma unroll
      for (int jt = 0; jt < 4; ++jt) {
        const int ksw = jt >> 1;
        const int gkw = (jt & 1) * 2 + (n >> 3);
        const int jw  = n & 7;
        #pragma unroll
        for (int rr = 0; rr < 4; ++rr) {
          float z  = RCP(1.0f + EXP2(-C[jt][0][rr]));
          float rg = RCP(1.0f + EXP2(-C[jt][1][rr]));
          float y  = C[jt][2][rr] + rg * C[jt][3][rr];
          float cand = 1.0f - 2.0f * RCP(EXP2(y) + 1.0f);
          float hv = cand + z * (hold[jt * 4 + rr] - cand);
          hold[jt * 4 + rr] = hv;
          int off = ((ksw * 4 + gkw) * 16 + (g * 4 + rr)) * 8 + jw;
          nxt[off] = __builtin_bit_cast(unsigned short, (_Float16)hv);
        }
      }
      // next-step A-frag reads (same-wave DS ops in order -> see the writes);
      // latency hides under softmax below.
      #pragma unroll
      for (int ks = 0; ks < 2; ++ks) {
        int off = ((ks * 4 + g) * 16 + n) * 8;
        Ah[ks] = *(const f16x8*)(nxt + off);
      }
    }

    // ---- softmax + probs stores (off the critical path) ----
    #pragma unroll
    for (int rr = 0; rr < 4; ++rr) {
      float e0 = EXP2(L[0][rr]);
      float e1 = EXP2(L[1][rr]);
      float e2 = EXP2(L[2][rr]);
      float e3 = EXP2(L[3][rr]);
      float e4 = (n < 14) ? EXP2(L[4][rr]) : 0.0f;
      float sm = e0 + e1 + e2 + e3 + e4;
      sm += dppror<0x128>(sm);
      sm += dppror<0x124>(sm);
      sm += dppror<0x122>(sm);
      sm += dppror<0x121>(sm);
      float inv = RCP(sm);
      size_t grow = (size_t)myrow0 + g * 4 + rr;
      float* orow = out + (grow * 25 + s) * 78;
      orow[n]      = e0 * inv;
      orow[16 + n] = e1 * inv;
      orow[32 + n] = e2 * inv;
      orow[48 + n] = e3 * inv;
      if (n < 14) orow[64 + n] = e4 * inv;
    }
  }
}

extern "C" void kernel_launch(void* const* d_in, const int* in_sizes, int n_in,
                              void* d_out, int out_size, void* d_ws, size_t ws_size,
                              hipStream_t stream) {
  const float* x   = (const float*)d_in[0];
  const float* H   = (const float*)d_in[1];
  const float* Wk  = (const float*)d_in[2];
  const float* Uk  = (const float*)d_in[3];
  const float* b   = (const float*)d_in[4];
  const float* Wd  = (const float*)d_in[5];
  const float* bd  = (const float*)d_in[6];
  float* out = (float*)d_out;
  (void)d_ws; (void)ws_size; (void)in_sizes; (void)n_in; (void)out_size;

  const int lds = 18944 * 4;  // 75776 B -> 1 block/CU (grid-capped anyway)
  hipFuncSetAttribute((const void*)vgru_all,
                      hipFuncAttributeMaxDynamicSharedMemorySize, lds);
  vgru_all<<<dim3(256), dim3(TPB), lds, stream>>>(x, H, Wk, Uk, b, Wd, bd, out);
}